// Round 3
// baseline (1081.638 us; speedup 1.0000x reference)
//
#include <hip/hip_runtime.h>

typedef unsigned short u16;
typedef unsigned int   u32;

#define L_SEQ    2048
#define D_MODEL  1024
#define D_STATE  128
#define D_INNER  2048
#define NHEADS   32
#define HEADDIM  64
#define CONV_DIM 2304
#define D_IN_PROJ 4384
#define EPSF     1e-5f
#define NC       8          // scan chunks
#define CL       256        // chunk length

using frag  = __attribute__((ext_vector_type(8))) short;
using f32x4 = __attribute__((ext_vector_type(4))) float;
typedef __attribute__((ext_vector_type(8))) unsigned short u16x8;

__device__ __forceinline__ u16 f2bf(float f) {
  u32 u = __float_as_uint(f);
  return (u16)((u + 0x7fffu + ((u >> 16) & 1u)) >> 16);
}
__device__ __forceinline__ float bf2f(u16 u) {
  return __uint_as_float(((u32)u) << 16);
}
__device__ __forceinline__ void async16(const void* g, void* l) {
  __builtin_amdgcn_global_load_lds((const __attribute__((address_space(1))) u32*)g,
                                   (__attribute__((address_space(3))) u32*)l, 16, 0, 0);
}

// ---------------- zero helper ----------------
__global__ __launch_bounds__(256) void k_zero(u16* __restrict__ p, int n4) {
  int i = blockIdx.x * 256 + threadIdx.x;
  if (i < n4) ((ushort4*)p)[i] = ushort4{0, 0, 0, 0};
}

// ---------------- fp32 -> bf16 convert ----------------
__global__ __launch_bounds__(256) void k_cvt(const float* __restrict__ in,
                                             u16* __restrict__ out, int n4) {
  int i = blockIdx.x * 256 + threadIdx.x;
  if (i < n4) {
    float4 v = ((const float4*)in)[i];
    ushort4 o;
    o.x = f2bf(v.x); o.y = f2bf(v.y); o.z = f2bf(v.z); o.w = f2bf(v.w);
    ((ushort4*)out)[i] = o;
  }
}

// ---------------- bf16 MFMA GEMM:  C[M][ldc] = A[M][K] * B[N][K]^T ----------------
template <int BF16OUT>
__global__ __launch_bounds__(256) void k_gemm(const u16* __restrict__ A,
                                              const u16* __restrict__ B, int K,
                                              int Nvalid, int ldc,
                                              u16* __restrict__ Cb,
                                              float* __restrict__ Cf,
                                              const float* __restrict__ resid,
                                              float* __restrict__ Cdt) {
  __shared__ __attribute__((aligned(16))) u16 As[128 * 32];
  __shared__ __attribute__((aligned(16))) u16 Bs[128 * 32];
  const int tid = threadIdx.x;
  const int lane = tid & 63;
  const int wid = tid >> 6;
  const int wm = wid >> 1, wn = wid & 1;
  const int m0 = blockIdx.x * 128, n0 = blockIdx.y * 128;

  f32x4 acc[4][4];
#pragma unroll
  for (int i = 0; i < 4; ++i)
#pragma unroll
    for (int j = 0; j < 4; ++j) acc[i][j] = f32x4{0.f, 0.f, 0.f, 0.f};

  const char* gA[2]; const char* gB[2]; char* lA[2]; char* lB[2];
#pragma unroll
  for (int j = 0; j < 2; ++j) {
    int base = (wid * 2 + j) * 1024;
    int p = base + lane * 16;
    int row = p >> 6;
    int colb = p & 63;
    gA[j] = (const char*)A + ((size_t)(m0 + row) * K) * 2 + colb;
    gB[j] = (const char*)B + ((size_t)(n0 + row) * K) * 2 + colb;
    lA[j] = (char*)As + base;
    lB[j] = (char*)Bs + base;
  }

  const int kg = (lane >> 4) * 16;
  const int rr = wm * 64 + (lane & 15);
  const int cc = wn * 64 + (lane & 15);

  for (int k0 = 0; k0 < K; k0 += 32) {
    size_t kb = (size_t)k0 * 2;
    async16(gA[0] + kb, lA[0]);
    async16(gA[1] + kb, lA[1]);
    async16(gB[0] + kb, lB[0]);
    async16(gB[1] + kb, lB[1]);
    __syncthreads();
    frag af[4], bfr[4];
#pragma unroll
    for (int mi = 0; mi < 4; ++mi)
      af[mi] = *(const frag*)((const char*)As + (rr + mi * 16) * 64 + kg);
#pragma unroll
    for (int ni = 0; ni < 4; ++ni)
      bfr[ni] = *(const frag*)((const char*)Bs + (cc + ni * 16) * 64 + kg);
#pragma unroll
    for (int mi = 0; mi < 4; ++mi)
#pragma unroll
      for (int ni = 0; ni < 4; ++ni)
        acc[mi][ni] = __builtin_amdgcn_mfma_f32_16x16x32_bf16(af[mi], bfr[ni],
                                                              acc[mi][ni], 0, 0, 0);
    __syncthreads();
  }

  const int er = (lane >> 4) * 4;
  const int ec = lane & 15;
#pragma unroll
  for (int mi = 0; mi < 4; ++mi) {
#pragma unroll
    for (int ni = 0; ni < 4; ++ni) {
      int col = n0 + wn * 64 + ni * 16 + ec;
      if (col < Nvalid) {
#pragma unroll
        for (int r = 0; r < 4; ++r) {
          int row = m0 + wm * 64 + mi * 16 + er + r;
          size_t off = (size_t)row * ldc + col;
          float v = acc[mi][ni][r];
          if (BF16OUT) {
            Cb[off] = f2bf(v);
            if (col >= D_INNER + CONV_DIM)
              Cdt[(size_t)row * NHEADS + (col - D_INNER - CONV_DIM)] = v;
          } else {
            Cf[off] = v + resid[off];
          }
        }
      }
    }
  }
}

// ---------------- depthwise causal conv(4) + bias + silu ----------------
// channels < 2048 -> xcb bf16 (stride 2048); channels >= 2048 (B,C) -> bcf f32 (stride 256)
__global__ __launch_bounds__(256) void k_conv(const u16* __restrict__ zxb,
                                              const float* __restrict__ cw,
                                              const float* __restrict__ cb,
                                              u16* __restrict__ xcb,
                                              float* __restrict__ bcf) {
  int row = blockIdx.x;          // b*L + l
  int l = row & (L_SEQ - 1);
  for (int c4 = threadIdx.x; c4 < CONV_DIM / 4; c4 += 256) {
    int c = c4 * 4;
    float4 w0 = ((const float4*)cw)[c + 0];
    float4 w1 = ((const float4*)cw)[c + 1];
    float4 w2 = ((const float4*)cw)[c + 2];
    float4 w3 = ((const float4*)cw)[c + 3];
    float4 bias = *(const float4*)(cb + c);
    float a0 = bias.x, a1 = bias.y, a2 = bias.z, a3 = bias.w;
#pragma unroll
    for (int k = 0; k < 4; ++k) {
      int lm = l - 3 + k;
      if (lm >= 0) {
        ushort4 xv = *(const ushort4*)(zxb + (size_t)(row - 3 + k) * D_IN_PROJ + D_INNER + c);
        a0 = fmaf(bf2f(xv.x), (&w0.x)[k], a0);
        a1 = fmaf(bf2f(xv.y), (&w1.x)[k], a1);
        a2 = fmaf(bf2f(xv.z), (&w2.x)[k], a2);
        a3 = fmaf(bf2f(xv.w), (&w3.x)[k], a3);
      }
    }
    a0 = a0 / (1.f + expf(-a0));
    a1 = a1 / (1.f + expf(-a1));
    a2 = a2 / (1.f + expf(-a2));
    a3 = a3 / (1.f + expf(-a3));
    if (c < D_INNER) {
      ushort4 o;
      o.x = f2bf(a0); o.y = f2bf(a1); o.z = f2bf(a2); o.w = f2bf(a3);
      *(ushort4*)(xcb + (size_t)row * D_INNER + c) = o;
    } else {
      *(float4*)(bcf + (size_t)row * 256 + (c - D_INNER)) = float4{a0, a1, a2, a3};
    }
  }
}

// ---------------- dt = softplus(raw+bias), dA = exp(dt*A); -> [b][h][l] ----------------
__global__ __launch_bounds__(256) void k_dt(const float* __restrict__ dtf,
                                            const float* __restrict__ dtb,
                                            const float* __restrict__ alog,
                                            float* __restrict__ dtv,
                                            float* __restrict__ dAv) {
  int idx = blockIdx.x * 256 + threadIdx.x;  // (b*L + l)*32 + h
  int h = idx & 31;
  int row = idx >> 5;
  int l = row & (L_SEQ - 1);
  int b = row >> 11;
  float raw = dtf[(size_t)row * NHEADS + h] + dtb[h];
  float dt = raw > 20.f ? raw : log1pf(expf(raw));
  float A = -expf(alog[h]);
  size_t o = ((size_t)(b * NHEADS + h)) * L_SEQ + l;
  dtv[o] = dt;
  dAv[o] = expf(dt * A);
}

// ================= chunked scan =================
// state slot for (bh, c, ph, t): S[((bh*NC+c)*2+ph)*4096 + t*8 .. +8)
// pass 1: local scan per chunk (h0=0), store final state + chunk decay product P
__global__ __launch_bounds__(512) void k_scan1(const u16* __restrict__ xcb,
                                               const float* __restrict__ bcf,
                                               const float* __restrict__ dtv,
                                               const float* __restrict__ dAv,
                                               float* __restrict__ S,
                                               float* __restrict__ P) {
  int bid = blockIdx.x;            // (bh*2+ph)*7 + c   (chunk NC-1 skipped)
  int c = bid % (NC - 1);
  int bp = bid / (NC - 1);
  int ph = bp & 1;
  int bh = bp >> 1;
  int h = bh & 31, b = bh >> 5;
  int t = threadIdx.x;
  int pl = t >> 4, ng = t & 15;

  const float* dtp = dtv + (size_t)bh * L_SEQ;
  const float* dAp = dAv + (size_t)bh * L_SEQ;
  const u16* xrow = xcb + (size_t)b * L_SEQ * D_INNER;
  const float* bcrow = bcf + (size_t)b * L_SEQ * 256;
  const int xoff = h * HEADDIM + ph * 32 + pl;
  const int boff = ng * 8;
  const int l0 = c * CL, lend = l0 + CL;

  float s[8];
#pragma unroll
  for (int i = 0; i < 8; ++i) s[i] = 0.f;
  float ap = 1.f;

  float p_dt = dtp[l0], p_dA = dAp[l0];
  u16 p_x = xrow[(size_t)l0 * D_INNER + xoff];
  float4 pB0 = *(const float4*)(bcrow + (size_t)l0 * 256 + boff);
  float4 pB1 = *(const float4*)(bcrow + (size_t)l0 * 256 + boff + 4);

  for (int l = l0; l < lend; ++l) {
    float c_dt = p_dt, c_dA = p_dA;
    u16 cx = p_x;
    float4 cB0 = pB0, cB1 = pB1;
    if (l + 1 < lend) {
      p_dt = dtp[l + 1]; p_dA = dAp[l + 1];
      p_x = xrow[(size_t)(l + 1) * D_INNER + xoff];
      pB0 = *(const float4*)(bcrow + (size_t)(l + 1) * 256 + boff);
      pB1 = *(const float4*)(bcrow + (size_t)(l + 1) * 256 + boff + 4);
    }
    float dtx = c_dt * bf2f(cx);
    s[0] = fmaf(s[0], c_dA, dtx * cB0.x);
    s[1] = fmaf(s[1], c_dA, dtx * cB0.y);
    s[2] = fmaf(s[2], c_dA, dtx * cB0.z);
    s[3] = fmaf(s[3], c_dA, dtx * cB0.w);
    s[4] = fmaf(s[4], c_dA, dtx * cB1.x);
    s[5] = fmaf(s[5], c_dA, dtx * cB1.y);
    s[6] = fmaf(s[6], c_dA, dtx * cB1.z);
    s[7] = fmaf(s[7], c_dA, dtx * cB1.w);
    ap *= c_dA;
  }
  float* slot = S + ((size_t)(bh * NC + c) * 2 + ph) * 4096 + t * 8;
  *(float4*)slot = float4{s[0], s[1], s[2], s[3]};
  *(float4*)(slot + 4) = float4{s[4], s[5], s[6], s[7]};
  if (t == 0 && ph == 0) P[bh * NC + c] = ap;
}

// pass 2: sequential inter-chunk combine, in place: slot c becomes H[c] (chunk-start state)
__global__ __launch_bounds__(512) void k_scan2(float* __restrict__ S,
                                               const float* __restrict__ P) {
  int bp = blockIdx.x;            // bh*2+ph
  int ph = bp & 1;
  int bh = bp >> 1;
  int t = threadIdx.x;
  float r[8];
#pragma unroll
  for (int i = 0; i < 8; ++i) r[i] = 0.f;
  for (int c = 0; c < NC; ++c) {
    float* slot = S + ((size_t)(bh * NC + c) * 2 + ph) * 4096 + t * 8;
    if (c < NC - 1) {
      float4 t0 = *(const float4*)slot;
      float4 t1 = *(const float4*)(slot + 4);
      float pc = P[bh * NC + c];
      *(float4*)slot = float4{r[0], r[1], r[2], r[3]};
      *(float4*)(slot + 4) = float4{r[4], r[5], r[6], r[7]};
      r[0] = fmaf(r[0], pc, t0.x); r[1] = fmaf(r[1], pc, t0.y);
      r[2] = fmaf(r[2], pc, t0.z); r[3] = fmaf(r[3], pc, t0.w);
      r[4] = fmaf(r[4], pc, t1.x); r[5] = fmaf(r[5], pc, t1.y);
      r[6] = fmaf(r[6], pc, t1.z); r[7] = fmaf(r[7], pc, t1.w);
    } else {
      *(float4*)slot = float4{r[0], r[1], r[2], r[3]};
      *(float4*)(slot + 4) = float4{r[4], r[5], r[6], r[7]};
    }
  }
}

// pass 3: full scan per chunk seeded with H[c]; writes y (bf16)
__global__ __launch_bounds__(512) void k_scan3(const u16* __restrict__ xcb,
                                               const float* __restrict__ bcf,
                                               const float* __restrict__ dtv,
                                               const float* __restrict__ dAv,
                                               const float* __restrict__ S,
                                               u16* __restrict__ ysb) {
  int bid = blockIdx.x;            // (bh*2+ph)*NC + c
  int c = bid & (NC - 1);
  int bp = bid >> 3;
  int ph = bp & 1;
  int bh = bp >> 1;
  int h = bh & 31, b = bh >> 5;
  int t = threadIdx.x;
  int pl = t >> 4, ng = t & 15;

  const float* dtp = dtv + (size_t)bh * L_SEQ;
  const float* dAp = dAv + (size_t)bh * L_SEQ;
  const u16* xrow = xcb + (size_t)b * L_SEQ * D_INNER;
  const float* bcrow = bcf + (size_t)b * L_SEQ * 256;
  const int xoff = h * HEADDIM + ph * 32 + pl;
  const int boff = ng * 8;
  const int coff = 128 + ng * 8;
  const int l0 = c * CL, lend = l0 + CL;
  u16* yout = ysb + (size_t)b * L_SEQ * D_INNER + xoff;

  const float* slot = S + ((size_t)(bh * NC + c) * 2 + ph) * 4096 + t * 8;
  float4 s0 = *(const float4*)slot;
  float4 s1 = *(const float4*)(slot + 4);
  float s[8] = {s0.x, s0.y, s0.z, s0.w, s1.x, s1.y, s1.z, s1.w};

  float p_dt = dtp[l0], p_dA = dAp[l0];
  u16 p_x = xrow[(size_t)l0 * D_INNER + xoff];
  float4 pB0 = *(const float4*)(bcrow + (size_t)l0 * 256 + boff);
  float4 pB1 = *(const float4*)(bcrow + (size_t)l0 * 256 + boff + 4);
  float4 pC0 = *(const float4*)(bcrow + (size_t)l0 * 256 + coff);
  float4 pC1 = *(const float4*)(bcrow + (size_t)l0 * 256 + coff + 4);

  for (int l = l0; l < lend; ++l) {
    float c_dt = p_dt, c_dA = p_dA;
    u16 cx = p_x;
    float4 cB0 = pB0, cB1 = pB1, cC0 = pC0, cC1 = pC1;
    if (l + 1 < lend) {
      const float* nbc = bcrow + (size_t)(l + 1) * 256;
      p_dt = dtp[l + 1]; p_dA = dAp[l + 1];
      p_x = xrow[(size_t)(l + 1) * D_INNER + xoff];
      pB0 = *(const float4*)(nbc + boff);
      pB1 = *(const float4*)(nbc + boff + 4);
      pC0 = *(const float4*)(nbc + coff);
      pC1 = *(const float4*)(nbc + coff + 4);
    }
    float dtx = c_dt * bf2f(cx);
    float acc = 0.f;
    s[0] = fmaf(s[0], c_dA, dtx * cB0.x); acc = fmaf(s[0], cC0.x, acc);
    s[1] = fmaf(s[1], c_dA, dtx * cB0.y); acc = fmaf(s[1], cC0.y, acc);
    s[2] = fmaf(s[2], c_dA, dtx * cB0.z); acc = fmaf(s[2], cC0.z, acc);
    s[3] = fmaf(s[3], c_dA, dtx * cB0.w); acc = fmaf(s[3], cC0.w, acc);
    s[4] = fmaf(s[4], c_dA, dtx * cB1.x); acc = fmaf(s[4], cC1.x, acc);
    s[5] = fmaf(s[5], c_dA, dtx * cB1.y); acc = fmaf(s[5], cC1.y, acc);
    s[6] = fmaf(s[6], c_dA, dtx * cB1.z); acc = fmaf(s[6], cC1.z, acc);
    s[7] = fmaf(s[7], c_dA, dtx * cB1.w); acc = fmaf(s[7], cC1.w, acc);
    acc += __shfl_xor(acc, 1);
    acc += __shfl_xor(acc, 2);
    acc += __shfl_xor(acc, 4);
    acc += __shfl_xor(acc, 8);
    if (ng == 0) yout[(size_t)l * D_INNER] = f2bf(acc);
  }
}

// ---------------- y = (ys + D*x_ssm)*silu(z), RMSNorm, -> bf16 ----------------
__global__ __launch_bounds__(256) void k_gate(const u16* __restrict__ ysb,
                                              const u16* __restrict__ xcb,
                                              const u16* __restrict__ zxb,
                                              const float* __restrict__ Dp,
                                              const float* __restrict__ nw,
                                              u16* __restrict__ yb) {
  int row = blockIdx.x;
  int t = threadIdx.x;
  int d0 = t * 8;
  float Dh = Dp[d0 >> 6];
  u16x8 ya = *(const u16x8*)(ysb + (size_t)row * D_INNER + d0);
  u16x8 xa = *(const u16x8*)(xcb + (size_t)row * D_INNER + d0);
  u16x8 za = *(const u16x8*)(zxb + (size_t)row * D_IN_PROJ + d0);
  float v[8];
  float ss = 0.f;
#pragma unroll
  for (int c = 0; c < 8; ++c) {
    float val = bf2f(ya[c]) + Dh * bf2f(xa[c]);
    float zz = bf2f(za[c]);
    val *= zz / (1.f + expf(-zz));
    v[c] = val;
    ss += val * val;
  }
  __shared__ float red[4];
#pragma unroll
  for (int off = 32; off; off >>= 1) ss += __shfl_xor(ss, off);
  if ((t & 63) == 0) red[t >> 6] = ss;
  __syncthreads();
  float tot = red[0] + red[1] + red[2] + red[3];
  float scale = rsqrtf(tot * (1.f / D_INNER) + EPSF);
  float4 w0 = *(const float4*)(nw + d0);
  float4 w1 = *(const float4*)(nw + d0 + 4);
  u16x8 o;
  o[0] = f2bf(v[0] * scale * w0.x);
  o[1] = f2bf(v[1] * scale * w0.y);
  o[2] = f2bf(v[2] * scale * w0.z);
  o[3] = f2bf(v[3] * scale * w0.w);
  o[4] = f2bf(v[4] * scale * w1.x);
  o[5] = f2bf(v[5] * scale * w1.y);
  o[6] = f2bf(v[6] * scale * w1.z);
  o[7] = f2bf(v[7] * scale * w1.w);
  *(u16x8*)(yb + (size_t)row * D_INNER + d0) = o;
}

// ---------------- final LayerNorm (in-place on d_out) ----------------
union F4 { float4 v; float f[4]; };
__global__ __launch_bounds__(256) void k_ln(float* __restrict__ io,
                                            const float* __restrict__ lw,
                                            const float* __restrict__ lb) {
  int row = blockIdx.x;
  int t = threadIdx.x;
  int d0 = t * 4;
  F4 v; v.v = *(const float4*)(io + (size_t)row * D_MODEL + d0);
  float s1 = v.f[0] + v.f[1] + v.f[2] + v.f[3];
  float s2 = v.f[0] * v.f[0] + v.f[1] * v.f[1] + v.f[2] * v.f[2] + v.f[3] * v.f[3];
  __shared__ float r1[4], r2[4];
#pragma unroll
  for (int off = 32; off; off >>= 1) {
    s1 += __shfl_xor(s1, off);
    s2 += __shfl_xor(s2, off);
  }
  if ((t & 63) == 0) { r1[t >> 6] = s1; r2[t >> 6] = s2; }
  __syncthreads();
  float S1 = r1[0] + r1[1] + r1[2] + r1[3];
  float S2 = r2[0] + r2[1] + r2[2] + r2[3];
  float mu = S1 * (1.f / D_MODEL);
  float var = S2 * (1.f / D_MODEL) - mu * mu;
  float inv = rsqrtf(var + EPSF);
  F4 w, bb, o;
  w.v = *(const float4*)(lw + d0);
  bb.v = *(const float4*)(lb + d0);
#pragma unroll
  for (int c = 0; c < 4; ++c) o.f[c] = (v.f[c] - mu) * inv * w.f[c] + bb.f[c];
  *(float4*)(io + (size_t)row * D_MODEL + d0) = o.v;
}

extern "C" void kernel_launch(void* const* d_in, const int* in_sizes, int n_in,
                              void* d_out, int out_size, void* d_ws, size_t ws_size,
                              hipStream_t stream) {
  const float* x    = (const float*)d_in[0];
  const float* w1   = (const float*)d_in[1];
  const float* cw   = (const float*)d_in[2];
  const float* cb   = (const float*)d_in[3];
  const float* dtb  = (const float*)d_in[4];
  const float* alog = (const float*)d_in[5];
  const float* Dp   = (const float*)d_in[6];
  const float* nw   = (const float*)d_in[7];
  const float* w2   = (const float*)d_in[8];
  const float* lw   = (const float*)d_in[9];
  const float* lb   = (const float*)d_in[10];
  float* out = (float*)d_out;
  char* ws = (char*)d_ws;

  // workspace layout (bytes)                               size
  u16*   xb  = (u16*)(ws + 0);            // 8192x1024 bf16  16,777,216
  u16*   w1b = (u16*)(ws + 16777216);     // 4480x1024 bf16   9,175,040
  u16*   w2b = (u16*)(ws + 25952256);     // 1024x2048 bf16   4,194,304
  u16*   zxb = (u16*)(ws + 30146560);     // 8192x4384 bf16  71,827,456
  u16*   xcb = (u16*)(ws + 101974016);    // 8192x2048 bf16  33,554,432
  float* dtf = (float*)(ws + 135528448);  // 8192x32 f32      1,048,576
  float* dtv = (float*)(ws + 136577024);  // 128x2048 f32     1,048,576
  float* dAv = (float*)(ws + 137625600);  // 128x2048 f32     1,048,576
  u16*   ysb = (u16*)(ws + 138674176);    // 8192x2048 bf16  33,554,432
  u16*   yb  = (u16*)(ws + 172228608);    // 8192x2048 bf16  33,554,432
  // total: 205,783,040 bytes
  if (ws_size < (size_t)205783040) return;

  float* bcf = out;                       // d_out as B/C f32 scratch (8192x256) until out_proj
  float* Sst = (float*)yb;                // chunk states (32 MiB) in yb until k_gate
  float* Pst = dtf;                       // chunk decay products (4 KiB), dtf free after k_dt

  k_zero<<<96, 256, 0, stream>>>(w1b + (size_t)4384 * 1024, 24576);

  k_cvt<<<8192, 256, 0, stream>>>(x, xb, 2097152);
  k_cvt<<<4384, 256, 0, stream>>>(w1, w1b, 1122304);
  k_cvt<<<2048, 256, 0, stream>>>(w2, w2b, 524288);

  // in_proj: zx[8192][4384] = xb @ w1b^T  (bf16 out + f32 dt copy)
  k_gemm<1><<<dim3(64, 35), 256, 0, stream>>>(xb, w1b, 1024, 4384, 4384,
                                              zxb, nullptr, nullptr, dtf);

  k_conv<<<8192, 256, 0, stream>>>(zxb, cw, cb, xcb, bcf);
  k_dt<<<1024, 256, 0, stream>>>(dtf, dtb, alog, dtv, dAv);

  k_scan1<<<128 * 2 * (NC - 1), 512, 0, stream>>>(xcb, bcf, dtv, dAv, Sst, Pst);
  k_scan2<<<256, 512, 0, stream>>>(Sst, Pst);
  k_scan3<<<128 * 2 * NC, 512, 0, stream>>>(xcb, bcf, dtv, dAv, Sst, ysb);

  k_gate<<<8192, 256, 0, stream>>>(ysb, xcb, zxb, Dp, nw, yb);

  // out_proj + residual: out = yb @ w2b^T + x
  k_gemm<0><<<dim3(64, 8), 256, 0, stream>>>(yb, w2b, 2048, 1024, 1024,
                                             nullptr, out, x, nullptr);

  k_ln<<<8192, 256, 0, stream>>>(out, lw, lb);
}

// Round 4
// 418.193 us; speedup vs baseline: 2.5865x; 2.5865x over previous
//
#include <hip/hip_runtime.h>

typedef unsigned short u16;
typedef unsigned int   u32;

#define L_SEQ    2048
#define D_MODEL  1024
#define D_STATE  128
#define D_INNER  2048
#define NHEADS   32
#define HEADDIM  64
#define CONV_DIM 2304
#define D_IN_PROJ 4384
#define EPSF     1e-5f
#define QC       128        // SSD chunk length
#define NCH      16         // chunks = L_SEQ/QC

using frag  = __attribute__((ext_vector_type(8))) short;
using f32x4 = __attribute__((ext_vector_type(4))) float;
typedef __attribute__((ext_vector_type(8))) unsigned short u16x8;

__device__ __forceinline__ u16 f2bf(float f) {
  u32 u = __float_as_uint(f);
  return (u16)((u + 0x7fffu + ((u >> 16) & 1u)) >> 16);
}
__device__ __forceinline__ float bf2f(u16 u) {
  return __uint_as_float(((u32)u) << 16);
}
__device__ __forceinline__ void async16(const void* g, void* l) {
  __builtin_amdgcn_global_load_lds((const __attribute__((address_space(1))) u32*)g,
                                   (__attribute__((address_space(3))) u32*)l, 16, 0, 0);
}

// ---------------- zero helper ----------------
__global__ __launch_bounds__(256) void k_zero(u16* __restrict__ p, int n4) {
  int i = blockIdx.x * 256 + threadIdx.x;
  if (i < n4) ((ushort4*)p)[i] = ushort4{0, 0, 0, 0};
}

// ---------------- fp32 -> bf16 convert ----------------
__global__ __launch_bounds__(256) void k_cvt(const float* __restrict__ in,
                                             u16* __restrict__ out, int n4) {
  int i = blockIdx.x * 256 + threadIdx.x;
  if (i < n4) {
    float4 v = ((const float4*)in)[i];
    ushort4 o;
    o.x = f2bf(v.x); o.y = f2bf(v.y); o.z = f2bf(v.z); o.w = f2bf(v.w);
    ((ushort4*)out)[i] = o;
  }
}

// ---------------- bf16 MFMA GEMM:  C[M][ldc] = A[M][K] * B[N][K]^T ----------------
template <int BF16OUT>
__global__ __launch_bounds__(256) void k_gemm(const u16* __restrict__ A,
                                              const u16* __restrict__ B, int K,
                                              int Nvalid, int ldc,
                                              u16* __restrict__ Cb,
                                              float* __restrict__ Cf,
                                              const float* __restrict__ resid,
                                              float* __restrict__ Cdt) {
  __shared__ __attribute__((aligned(16))) u16 As[128 * 32];
  __shared__ __attribute__((aligned(16))) u16 Bs[128 * 32];
  const int tid = threadIdx.x;
  const int lane = tid & 63;
  const int wid = tid >> 6;
  const int wm = wid >> 1, wn = wid & 1;
  const int m0 = blockIdx.x * 128, n0 = blockIdx.y * 128;

  f32x4 acc[4][4];
#pragma unroll
  for (int i = 0; i < 4; ++i)
#pragma unroll
    for (int j = 0; j < 4; ++j) acc[i][j] = f32x4{0.f, 0.f, 0.f, 0.f};

  const char* gA[2]; const char* gB[2]; char* lA[2]; char* lB[2];
#pragma unroll
  for (int j = 0; j < 2; ++j) {
    int base = (wid * 2 + j) * 1024;
    int p = base + lane * 16;
    int row = p >> 6;
    int colb = p & 63;
    gA[j] = (const char*)A + ((size_t)(m0 + row) * K) * 2 + colb;
    gB[j] = (const char*)B + ((size_t)(n0 + row) * K) * 2 + colb;
    lA[j] = (char*)As + base;
    lB[j] = (char*)Bs + base;
  }

  const int kg = (lane >> 4) * 16;
  const int rr = wm * 64 + (lane & 15);
  const int cc = wn * 64 + (lane & 15);

  for (int k0 = 0; k0 < K; k0 += 32) {
    size_t kb = (size_t)k0 * 2;
    async16(gA[0] + kb, lA[0]);
    async16(gA[1] + kb, lA[1]);
    async16(gB[0] + kb, lB[0]);
    async16(gB[1] + kb, lB[1]);
    __syncthreads();
    frag af[4], bfr[4];
#pragma unroll
    for (int mi = 0; mi < 4; ++mi)
      af[mi] = *(const frag*)((const char*)As + (rr + mi * 16) * 64 + kg);
#pragma unroll
    for (int ni = 0; ni < 4; ++ni)
      bfr[ni] = *(const frag*)((const char*)Bs + (cc + ni * 16) * 64 + kg);
#pragma unroll
    for (int mi = 0; mi < 4; ++mi)
#pragma unroll
      for (int ni = 0; ni < 4; ++ni)
        acc[mi][ni] = __builtin_amdgcn_mfma_f32_16x16x32_bf16(af[mi], bfr[ni],
                                                              acc[mi][ni], 0, 0, 0);
    __syncthreads();
  }

  const int er = (lane >> 4) * 4;
  const int ec = lane & 15;
#pragma unroll
  for (int mi = 0; mi < 4; ++mi) {
#pragma unroll
    for (int ni = 0; ni < 4; ++ni) {
      int col = n0 + wn * 64 + ni * 16 + ec;
      if (col < Nvalid) {
#pragma unroll
        for (int r = 0; r < 4; ++r) {
          int row = m0 + wm * 64 + mi * 16 + er + r;
          size_t off = (size_t)row * ldc + col;
          float v = acc[mi][ni][r];
          if (BF16OUT) {
            Cb[off] = f2bf(v);
            if (col >= D_INNER + CONV_DIM)
              Cdt[(size_t)row * NHEADS + (col - D_INNER - CONV_DIM)] = v;
          } else {
            Cf[off] = v + resid[off];
          }
        }
      }
    }
  }
}

// ---------------- depthwise causal conv(4) + bias + silu ----------------
__global__ __launch_bounds__(256) void k_conv(const u16* __restrict__ zxb,
                                              const float* __restrict__ cw,
                                              const float* __restrict__ cb,
                                              u16* __restrict__ xcb,
                                              float* __restrict__ bcf) {
  int row = blockIdx.x;          // b*L + l
  int l = row & (L_SEQ - 1);
  for (int c4 = threadIdx.x; c4 < CONV_DIM / 4; c4 += 256) {
    int c = c4 * 4;
    float4 w0 = ((const float4*)cw)[c + 0];
    float4 w1 = ((const float4*)cw)[c + 1];
    float4 w2 = ((const float4*)cw)[c + 2];
    float4 w3 = ((const float4*)cw)[c + 3];
    float4 bias = *(const float4*)(cb + c);
    float a0 = bias.x, a1 = bias.y, a2 = bias.z, a3 = bias.w;
#pragma unroll
    for (int k = 0; k < 4; ++k) {
      int lm = l - 3 + k;
      if (lm >= 0) {
        ushort4 xv = *(const ushort4*)(zxb + (size_t)(row - 3 + k) * D_IN_PROJ + D_INNER + c);
        a0 = fmaf(bf2f(xv.x), (&w0.x)[k], a0);
        a1 = fmaf(bf2f(xv.y), (&w1.x)[k], a1);
        a2 = fmaf(bf2f(xv.z), (&w2.x)[k], a2);
        a3 = fmaf(bf2f(xv.w), (&w3.x)[k], a3);
      }
    }
    a0 = a0 / (1.f + expf(-a0));
    a1 = a1 / (1.f + expf(-a1));
    a2 = a2 / (1.f + expf(-a2));
    a3 = a3 / (1.f + expf(-a3));
    if (c < D_INNER) {
      ushort4 o;
      o.x = f2bf(a0); o.y = f2bf(a1); o.z = f2bf(a2); o.w = f2bf(a3);
      *(ushort4*)(xcb + (size_t)row * D_INNER + c) = o;
    } else {
      *(float4*)(bcf + (size_t)row * 256 + (c - D_INNER)) = float4{a0, a1, a2, a3};
    }
  }
}

// ---------------- dt, and in-chunk inclusive cumsum of dt*A ----------------
// grid: bh(128) x chunk(16), 128 threads; writes dtv[bh][l], cumv[bh][l]
__global__ __launch_bounds__(128) void k_cum(const float* __restrict__ dtf,
                                             const float* __restrict__ dtb,
                                             const float* __restrict__ alog,
                                             float* __restrict__ dtv,
                                             float* __restrict__ cumv) {
  int bid = blockIdx.x;
  int c = bid & (NCH - 1);
  int bh = bid >> 4;
  int h = bh & 31, b = bh >> 5;
  int t = threadIdx.x;                 // 0..127
  int l = c * QC + t;
  float raw = dtf[((size_t)(b * L_SEQ + l)) * NHEADS + h] + dtb[h];
  float dt = raw > 20.f ? raw : log1pf(expf(raw));
  float A = -expf(alog[h]);
  float x = dt * A;
  int lane = t & 63;
#pragma unroll
  for (int off = 1; off < 64; off <<= 1) {
    float up = __shfl_up(x, off);
    if (lane >= off) x += up;
  }
  __shared__ float wtot;
  if (t == 63) wtot = x;
  __syncthreads();
  if (t >= 64) x += wtot;
  size_t o = (size_t)bh * L_SEQ + l;
  dtv[o] = dt;
  cumv[o] = x;
}

// ---------------- G = C @ B^T per (b, chunk)  [128x128, K=128] ----------------
__global__ __launch_bounds__(256) void k_g(const float* __restrict__ bcf,
                                           u16* __restrict__ Gb) {
  __shared__ u16 Cs[128 * 128];   // A-op: C rows i, k=n
  __shared__ u16 Bs[128 * 128];   // B-op: B rows j, k=n
  int bid = blockIdx.x;
  int c = bid & (NCH - 1);
  int b = bid >> 4;
  int tid = threadIdx.x, lane = tid & 63, wid = tid >> 6;
  int wm = wid >> 1, wn = wid & 1;
  const float* base = bcf + (size_t)(b * L_SEQ + c * QC) * 256;
  for (int idx = tid; idx < 128 * 32; idx += 256) {
    int row = idx >> 5, seg = idx & 31;
    float4 bv = *(const float4*)(base + (size_t)row * 256 + seg * 4);
    float4 cv = *(const float4*)(base + (size_t)row * 256 + 128 + seg * 4);
    ushort4 ob, oc;
    ob.x = f2bf(bv.x); ob.y = f2bf(bv.y); ob.z = f2bf(bv.z); ob.w = f2bf(bv.w);
    oc.x = f2bf(cv.x); oc.y = f2bf(cv.y); oc.z = f2bf(cv.z); oc.w = f2bf(cv.w);
    *(ushort4*)&Bs[row * 128 + seg * 4] = ob;
    *(ushort4*)&Cs[row * 128 + seg * 4] = oc;
  }
  __syncthreads();
  f32x4 acc[4][4];
#pragma unroll
  for (int i = 0; i < 4; ++i)
#pragma unroll
    for (int j = 0; j < 4; ++j) acc[i][j] = f32x4{0.f, 0.f, 0.f, 0.f};
  int rr = wm * 64 + (lane & 15);
  int cc = wn * 64 + (lane & 15);
#pragma unroll
  for (int kk = 0; kk < 4; ++kk) {
    int ko = kk * 32 + (lane >> 4) * 8;
    frag af[4], bfr[4];
#pragma unroll
    for (int mi = 0; mi < 4; ++mi)
      af[mi] = *(const frag*)&Cs[(rr + mi * 16) * 128 + ko];
#pragma unroll
    for (int ni = 0; ni < 4; ++ni)
      bfr[ni] = *(const frag*)&Bs[(cc + ni * 16) * 128 + ko];
#pragma unroll
    for (int mi = 0; mi < 4; ++mi)
#pragma unroll
      for (int ni = 0; ni < 4; ++ni)
        acc[mi][ni] = __builtin_amdgcn_mfma_f32_16x16x32_bf16(af[mi], bfr[ni],
                                                              acc[mi][ni], 0, 0, 0);
  }
  u16* gbase = Gb + ((size_t)(b * NCH + c)) * 128 * 128;
  const int er = (lane >> 4) * 4;
  const int ec = lane & 15;
#pragma unroll
  for (int mi = 0; mi < 4; ++mi)
#pragma unroll
    for (int ni = 0; ni < 4; ++ni)
#pragma unroll
      for (int r = 0; r < 4; ++r) {
        int i = wm * 64 + mi * 16 + er + r;
        int j = wn * 64 + ni * 16 + ec;
        gbase[(size_t)i * 128 + j] = f2bf(acc[mi][ni][r]);
      }
}

// ---------------- chunk states: S[p][n] = sum_j X[j][p] * B[j][n] * w[j] ----------------
// grid: (b,h,c) = 2048; out SH bf16 [bh][c][64][128]
__global__ __launch_bounds__(256) void k_states(const u16* __restrict__ xcb,
                                                const float* __restrict__ bcf,
                                                const float* __restrict__ dtv,
                                                const float* __restrict__ cumv,
                                                u16* __restrict__ SH) {
  __shared__ u16 XT[64 * 136];     // A-op: X^T rows p, k=j
  __shared__ u16 BW[128 * 136];    // B-op: (wB)^T rows n, k=j
  __shared__ float wlds[128];
  int bid = blockIdx.x;
  int c = bid & (NCH - 1);
  int bh = bid >> 4;
  int h = bh & 31, b = bh >> 5;
  int tid = threadIdx.x, lane = tid & 63, wid = tid >> 6;
  int wm = wid >> 1, wn = wid & 1;
  int l0 = c * QC;
  size_t bhl = (size_t)bh * L_SEQ + l0;
  if (tid < 128) {
    float ce = cumv[bhl + 127];
    wlds[tid] = expf(ce - cumv[bhl + tid]) * dtv[bhl + tid];
  }
  // X^T scatter
  const u16* xbase = xcb + ((size_t)(b * L_SEQ + l0)) * D_INNER + h * HEADDIM;
  for (int idx = tid; idx < 128 * 8; idx += 256) {
    int j = idx >> 3, seg = idx & 7;
    u16x8 xv = *(const u16x8*)(xbase + (size_t)j * D_INNER + seg * 8);
#pragma unroll
    for (int k = 0; k < 8; ++k) XT[(seg * 8 + k) * 136 + j] = xv[k];
  }
  __syncthreads();
  // (wB)^T scatter
  const float* bbase = bcf + (size_t)(b * L_SEQ + l0) * 256;
  for (int idx = tid; idx < 128 * 32; idx += 256) {
    int j = idx >> 5, seg = idx & 31;
    float4 bv = *(const float4*)(bbase + (size_t)j * 256 + seg * 4);
    float w = wlds[j];
    BW[(seg * 4 + 0) * 136 + j] = f2bf(bv.x * w);
    BW[(seg * 4 + 1) * 136 + j] = f2bf(bv.y * w);
    BW[(seg * 4 + 2) * 136 + j] = f2bf(bv.z * w);
    BW[(seg * 4 + 3) * 136 + j] = f2bf(bv.w * w);
  }
  __syncthreads();
  f32x4 acc[2][4];
#pragma unroll
  for (int i = 0; i < 2; ++i)
#pragma unroll
    for (int j = 0; j < 4; ++j) acc[i][j] = f32x4{0.f, 0.f, 0.f, 0.f};
  int rr = wm * 32 + (lane & 15);
  int cc = wn * 64 + (lane & 15);
#pragma unroll
  for (int kk = 0; kk < 4; ++kk) {
    int ko = kk * 32 + (lane >> 4) * 8;
    frag af[2], bfr[4];
#pragma unroll
    for (int mi = 0; mi < 2; ++mi)
      af[mi] = *(const frag*)&XT[(rr + mi * 16) * 136 + ko];
#pragma unroll
    for (int ni = 0; ni < 4; ++ni)
      bfr[ni] = *(const frag*)&BW[(cc + ni * 16) * 136 + ko];
#pragma unroll
    for (int mi = 0; mi < 2; ++mi)
#pragma unroll
      for (int ni = 0; ni < 4; ++ni)
        acc[mi][ni] = __builtin_amdgcn_mfma_f32_16x16x32_bf16(af[mi], bfr[ni],
                                                              acc[mi][ni], 0, 0, 0);
  }
  u16* sbase = SH + ((size_t)(bh * NCH + c)) * (64 * 128);
  const int er = (lane >> 4) * 4;
  const int ec = lane & 15;
#pragma unroll
  for (int mi = 0; mi < 2; ++mi)
#pragma unroll
    for (int ni = 0; ni < 4; ++ni)
#pragma unroll
      for (int r = 0; r < 4; ++r) {
        int p = wm * 32 + mi * 16 + er + r;
        int n = wn * 64 + ni * 16 + ec;
        sbase[(size_t)p * 128 + n] = f2bf(acc[mi][ni][r]);
      }
}

// ---------------- inter-chunk chain (in place: slot c becomes H_in for chunk c) ----------------
__global__ __launch_bounds__(512) void k_chain(u16* __restrict__ SH,
                                               const float* __restrict__ cumv) {
  int bh = blockIdx.x;
  int t = threadIdx.x;
  u16* base = SH + (size_t)bh * NCH * (64 * 128) + t * 16;
  float H[16];
#pragma unroll
  for (int i = 0; i < 16; ++i) H[i] = 0.f;
  for (int c = 0; c < NCH; ++c) {
    u16x8 s0 = *(const u16x8*)(base + (size_t)c * 8192);
    u16x8 s1 = *(const u16x8*)(base + (size_t)c * 8192 + 8);
    float e = expf(cumv[(size_t)bh * L_SEQ + c * QC + 127]);
    u16x8 h0, h1;
#pragma unroll
    for (int k = 0; k < 8; ++k) { h0[k] = f2bf(H[k]); h1[k] = f2bf(H[k + 8]); }
    *(u16x8*)(base + (size_t)c * 8192) = h0;
    *(u16x8*)(base + (size_t)c * 8192 + 8) = h1;
#pragma unroll
    for (int k = 0; k < 8; ++k) {
      H[k] = fmaf(H[k], e, bf2f(s0[k]));
      H[k + 8] = fmaf(H[k + 8], e, bf2f(s1[k]));
    }
  }
}

// ---------------- Y = M@X^T + Ct@H^T per (b,h,c)  [128x64] ----------------
__global__ __launch_bounds__(256) void k_y(const u16* __restrict__ xcb,
                                           const float* __restrict__ bcf,
                                           const float* __restrict__ dtv,
                                           const float* __restrict__ cumv,
                                           const u16* __restrict__ Gb,
                                           const u16* __restrict__ SH,
                                           u16* __restrict__ ysb) {
  __shared__ u16 Abuf[128 * 136];
  __shared__ u16 Bbuf[64 * 136];
  __shared__ float cums[128], dts[128];
  int bid = blockIdx.x;
  int c = bid & (NCH - 1);
  int bh = bid >> 4;
  int h = bh & 31, b = bh >> 5;
  int tid = threadIdx.x, lane = tid & 63, wid = tid >> 6;
  int wm = wid >> 1, wn = wid & 1;
  int l0 = c * QC;
  size_t bhl = (size_t)bh * L_SEQ + l0;
  if (tid < 128) { cums[tid] = cumv[bhl + tid]; dts[tid] = dtv[bhl + tid]; }
  // X^T scatter into Bbuf (independent of cums)
  const u16* xbase = xcb + ((size_t)(b * L_SEQ + l0)) * D_INNER + h * HEADDIM;
  for (int idx = tid; idx < 128 * 8; idx += 256) {
    int j = idx >> 3, seg = idx & 7;
    u16x8 xv = *(const u16x8*)(xbase + (size_t)j * D_INNER + seg * 8);
#pragma unroll
    for (int k = 0; k < 8; ++k) Bbuf[(seg * 8 + k) * 136 + j] = xv[k];
  }
  __syncthreads();
  // M = mask(G) * exp(cum_i - cum_j) * dt_j  into Abuf
  const u16* gbase = Gb + ((size_t)(b * NCH + c)) * 128 * 128;
  for (int idx = tid; idx < 128 * 16; idx += 256) {
    int i = idx >> 4, seg = idx & 15;
    u16x8 g = *(const u16x8*)(gbase + (size_t)i * 128 + seg * 8);
    float ci = cums[i];
    u16x8 o;
#pragma unroll
    for (int k = 0; k < 8; ++k) {
      int j = seg * 8 + k;
      float m = (j <= i) ? bf2f(g[k]) * expf(ci - cums[j]) * dts[j] : 0.f;
      o[k] = f2bf(m);
    }
    *(u16x8*)&Abuf[i * 136 + seg * 8] = o;
  }
  __syncthreads();
  f32x4 acc[4][2];
#pragma unroll
  for (int i = 0; i < 4; ++i)
#pragma unroll
    for (int j = 0; j < 2; ++j) acc[i][j] = f32x4{0.f, 0.f, 0.f, 0.f};
  int rr = wm * 64 + (lane & 15);
  int cc = wn * 32 + (lane & 15);
#pragma unroll
  for (int kk = 0; kk < 4; ++kk) {
    int ko = kk * 32 + (lane >> 4) * 8;
    frag af[4], bfr[2];
#pragma unroll
    for (int mi = 0; mi < 4; ++mi)
      af[mi] = *(const frag*)&Abuf[(rr + mi * 16) * 136 + ko];
#pragma unroll
    for (int ni = 0; ni < 2; ++ni)
      bfr[ni] = *(const frag*)&Bbuf[(cc + ni * 16) * 136 + ko];
#pragma unroll
    for (int mi = 0; mi < 4; ++mi)
#pragma unroll
      for (int ni = 0; ni < 2; ++ni)
        acc[mi][ni] = __builtin_amdgcn_mfma_f32_16x16x32_bf16(af[mi], bfr[ni],
                                                              acc[mi][ni], 0, 0, 0);
  }
  __syncthreads();
  // pass 2: Ct[i][n] = C[i][n]*exp(cum_i); H[p][n]
  const float* cbase = bcf + (size_t)(b * L_SEQ + l0) * 256 + 128;
  for (int idx = tid; idx < 128 * 32; idx += 256) {
    int i = idx >> 5, seg = idx & 31;
    float4 cv = *(const float4*)(cbase + (size_t)i * 256 + seg * 4);
    float e = expf(cums[i]);
    ushort4 o;
    o.x = f2bf(cv.x * e); o.y = f2bf(cv.y * e);
    o.z = f2bf(cv.z * e); o.w = f2bf(cv.w * e);
    *(ushort4*)&Abuf[i * 136 + seg * 4] = o;
  }
  const u16* hbase = SH + ((size_t)(bh * NCH + c)) * (64 * 128);
  for (int idx = tid; idx < 64 * 16; idx += 256) {
    int p = idx >> 4, seg = idx & 15;
    *(u16x8*)&Bbuf[p * 136 + seg * 8] = *(const u16x8*)(hbase + (size_t)p * 128 + seg * 8);
  }
  __syncthreads();
#pragma unroll
  for (int kk = 0; kk < 4; ++kk) {
    int ko = kk * 32 + (lane >> 4) * 8;
    frag af[4], bfr[2];
#pragma unroll
    for (int mi = 0; mi < 4; ++mi)
      af[mi] = *(const frag*)&Abuf[(rr + mi * 16) * 136 + ko];
#pragma unroll
    for (int ni = 0; ni < 2; ++ni)
      bfr[ni] = *(const frag*)&Bbuf[(cc + ni * 16) * 136 + ko];
#pragma unroll
    for (int mi = 0; mi < 4; ++mi)
#pragma unroll
      for (int ni = 0; ni < 2; ++ni)
        acc[mi][ni] = __builtin_amdgcn_mfma_f32_16x16x32_bf16(af[mi], bfr[ni],
                                                              acc[mi][ni], 0, 0, 0);
  }
  const int er = (lane >> 4) * 4;
  const int ec = lane & 15;
#pragma unroll
  for (int mi = 0; mi < 4; ++mi)
#pragma unroll
    for (int ni = 0; ni < 2; ++ni)
#pragma unroll
      for (int r = 0; r < 4; ++r) {
        int i = wm * 64 + mi * 16 + er + r;
        int p = wn * 32 + ni * 16 + ec;
        ysb[((size_t)(b * L_SEQ + l0 + i)) * D_INNER + h * HEADDIM + p] =
            f2bf(acc[mi][ni][r]);
      }
}

// ---------------- y = (ys + D*x_ssm)*silu(z), RMSNorm, -> bf16 ----------------
__global__ __launch_bounds__(256) void k_gate(const u16* __restrict__ ysb,
                                              const u16* __restrict__ xcb,
                                              const u16* __restrict__ zxb,
                                              const float* __restrict__ Dp,
                                              const float* __restrict__ nw,
                                              u16* __restrict__ yb) {
  int row = blockIdx.x;
  int t = threadIdx.x;
  int d0 = t * 8;
  float Dh = Dp[d0 >> 6];
  u16x8 ya = *(const u16x8*)(ysb + (size_t)row * D_INNER + d0);
  u16x8 xa = *(const u16x8*)(xcb + (size_t)row * D_INNER + d0);
  u16x8 za = *(const u16x8*)(zxb + (size_t)row * D_IN_PROJ + d0);
  float v[8];
  float ss = 0.f;
#pragma unroll
  for (int c = 0; c < 8; ++c) {
    float val = bf2f(ya[c]) + Dh * bf2f(xa[c]);
    float zz = bf2f(za[c]);
    val *= zz / (1.f + expf(-zz));
    v[c] = val;
    ss += val * val;
  }
  __shared__ float red[4];
#pragma unroll
  for (int off = 32; off; off >>= 1) ss += __shfl_xor(ss, off);
  if ((t & 63) == 0) red[t >> 6] = ss;
  __syncthreads();
  float tot = red[0] + red[1] + red[2] + red[3];
  float scale = rsqrtf(tot * (1.f / D_INNER) + EPSF);
  float4 w0 = *(const float4*)(nw + d0);
  float4 w1 = *(const float4*)(nw + d0 + 4);
  u16x8 o;
  o[0] = f2bf(v[0] * scale * w0.x);
  o[1] = f2bf(v[1] * scale * w0.y);
  o[2] = f2bf(v[2] * scale * w0.z);
  o[3] = f2bf(v[3] * scale * w0.w);
  o[4] = f2bf(v[4] * scale * w1.x);
  o[5] = f2bf(v[5] * scale * w1.y);
  o[6] = f2bf(v[6] * scale * w1.z);
  o[7] = f2bf(v[7] * scale * w1.w);
  *(u16x8*)(yb + (size_t)row * D_INNER + d0) = o;
}

// ---------------- final LayerNorm (in-place on d_out) ----------------
union F4 { float4 v; float f[4]; };
__global__ __launch_bounds__(256) void k_ln(float* __restrict__ io,
                                            const float* __restrict__ lw,
                                            const float* __restrict__ lb) {
  int row = blockIdx.x;
  int t = threadIdx.x;
  int d0 = t * 4;
  F4 v; v.v = *(const float4*)(io + (size_t)row * D_MODEL + d0);
  float s1 = v.f[0] + v.f[1] + v.f[2] + v.f[3];
  float s2 = v.f[0] * v.f[0] + v.f[1] * v.f[1] + v.f[2] * v.f[2] + v.f[3] * v.f[3];
  __shared__ float r1[4], r2[4];
#pragma unroll
  for (int off = 32; off; off >>= 1) {
    s1 += __shfl_xor(s1, off);
    s2 += __shfl_xor(s2, off);
  }
  if ((t & 63) == 0) { r1[t >> 6] = s1; r2[t >> 6] = s2; }
  __syncthreads();
  float S1 = r1[0] + r1[1] + r1[2] + r1[3];
  float S2 = r2[0] + r2[1] + r2[2] + r2[3];
  float mu = S1 * (1.f / D_MODEL);
  float var = S2 * (1.f / D_MODEL) - mu * mu;
  float inv = rsqrtf(var + EPSF);
  F4 w, bb, o;
  w.v = *(const float4*)(lw + d0);
  bb.v = *(const float4*)(lb + d0);
#pragma unroll
  for (int c = 0; c < 4; ++c) o.f[c] = (v.f[c] - mu) * inv * w.f[c] + bb.f[c];
  *(float4*)(io + (size_t)row * D_MODEL + d0) = o.v;
}

extern "C" void kernel_launch(void* const* d_in, const int* in_sizes, int n_in,
                              void* d_out, int out_size, void* d_ws, size_t ws_size,
                              hipStream_t stream) {
  const float* x    = (const float*)d_in[0];
  const float* w1   = (const float*)d_in[1];
  const float* cw   = (const float*)d_in[2];
  const float* cb   = (const float*)d_in[3];
  const float* dtb  = (const float*)d_in[4];
  const float* alog = (const float*)d_in[5];
  const float* Dp   = (const float*)d_in[6];
  const float* nw   = (const float*)d_in[7];
  const float* w2   = (const float*)d_in[8];
  const float* lw   = (const float*)d_in[9];
  const float* lb   = (const float*)d_in[10];
  float* out = (float*)d_out;
  char* ws = (char*)d_ws;

  // workspace layout (bytes)
  u16*   xb   = (u16*)(ws + 0);            // 8192x1024 bf16  16,777,216
  u16*   w1b  = (u16*)(ws + 16777216);     // 4480x1024 bf16   9,175,040
  u16*   w2b  = (u16*)(ws + 25952256);     // 1024x2048 bf16   4,194,304
  u16*   zxb  = (u16*)(ws + 30146560);     // 8192x4384 bf16  71,827,456
  u16*   xcb  = (u16*)(ws + 101974016);    // 8192x2048 bf16  33,554,432
  float* dtf  = (float*)(ws + 135528448);  // 8192x32 f32      1,048,576
  float* dtv  = (float*)(ws + 136577024);  // 128x2048 f32     1,048,576
  float* cumv = (float*)(ws + 137625600);  // 128x2048 f32     1,048,576
  u16*   ysb  = (u16*)(ws + 138674176);    // 8192x2048 bf16  33,554,432
  u16*   yb   = (u16*)(ws + 172228608);    // 8192x2048 bf16  33,554,432
  u16*   Gb   = (u16*)(ws + 205783040);    // 64x128x128 bf16  4,194,304
  // total: 209,977,344 (proven available in round 2)
  if (ws_size < (size_t)209977344) return;

  float* bcf = out;          // d_out as B/C f32 scratch (8192x256) until out_proj
  u16*   SH  = yb;           // chunk states bf16 [bh][c][64][128] in yb until k_gate

  k_zero<<<96, 256, 0, stream>>>(w1b + (size_t)4384 * 1024, 24576);

  k_cvt<<<8192, 256, 0, stream>>>(x, xb, 2097152);
  k_cvt<<<4384, 256, 0, stream>>>(w1, w1b, 1122304);
  k_cvt<<<2048, 256, 0, stream>>>(w2, w2b, 524288);

  // in_proj: zx[8192][4384] = xb @ w1b^T (bf16 out + f32 dt copy)
  k_gemm<1><<<dim3(64, 35), 256, 0, stream>>>(xb, w1b, 1024, 4384, 4384,
                                              zxb, nullptr, nullptr, dtf);

  k_conv<<<8192, 256, 0, stream>>>(zxb, cw, cb, xcb, bcf);
  k_cum<<<128 * NCH, 128, 0, stream>>>(dtf, dtb, alog, dtv, cumv);

  k_g<<<4 * NCH, 256, 0, stream>>>(bcf, Gb);
  k_states<<<128 * NCH, 256, 0, stream>>>(xcb, bcf, dtv, cumv, SH);
  k_chain<<<128, 512, 0, stream>>>(SH, cumv);
  k_y<<<128 * NCH, 256, 0, stream>>>(xcb, bcf, dtv, cumv, Gb, SH, ysb);

  k_gate<<<8192, 256, 0, stream>>>(ysb, xcb, zxb, Dp, nw, yb);

  // out_proj + residual: out = yb @ w2b^T + x
  k_gemm<0><<<dim3(64, 8), 256, 0, stream>>>(yb, w2b, 2048, 1024, 1024,
                                             nullptr, out, x, nullptr);

  k_ln<<<8192, 256, 0, stream>>>(out, lw, lb);
}

// Round 5
// 381.710 us; speedup vs baseline: 2.8337x; 1.0956x over previous
//
#include <hip/hip_runtime.h>

typedef unsigned short u16;
typedef unsigned int   u32;

#define L_SEQ    2048
#define D_MODEL  1024
#define D_STATE  128
#define D_INNER  2048
#define NHEADS   32
#define HEADDIM  64
#define CONV_DIM 2304
#define D_IN_PROJ 4384
#define EPSF     1e-5f
#define QC       128        // SSD chunk length
#define NCH      16         // chunks = L_SEQ/QC

using frag  = __attribute__((ext_vector_type(8))) short;
using f32x4 = __attribute__((ext_vector_type(4))) float;
typedef __attribute__((ext_vector_type(8))) unsigned short u16x8;

__device__ __forceinline__ u16 f2bf(float f) {
  u32 u = __float_as_uint(f);
  return (u16)((u + 0x7fffu + ((u >> 16) & 1u)) >> 16);
}
__device__ __forceinline__ float bf2f(u16 u) {
  return __uint_as_float(((u32)u) << 16);
}
__device__ __forceinline__ void async16(const void* g, void* l) {
  __builtin_amdgcn_global_load_lds((const __attribute__((address_space(1))) u32*)g,
                                   (__attribute__((address_space(3))) u32*)l, 16, 0, 0);
}

// ---------------- fused fp32->bf16 converts + W1-tail zero ----------------
__global__ __launch_bounds__(256) void k_cvt_all(const float* __restrict__ x,
                                                 u16* __restrict__ xb,
                                                 const float* __restrict__ w1,
                                                 u16* __restrict__ w1b,
                                                 const float* __restrict__ w2,
                                                 u16* __restrict__ w2b) {
  int bid = blockIdx.x;
  int t = threadIdx.x;
  const float* src;
  u16* dst;
  int i;
  if (bid < 8192)       { i = bid * 256 + t;          src = x;  dst = xb;  }
  else if (bid < 12576) { i = (bid - 8192) * 256 + t; src = w1; dst = w1b; }
  else if (bid < 14624) { i = (bid - 12576) * 256 + t; src = w2; dst = w2b; }
  else {  // zero pad rows 4384..4479 of w1b
    i = (bid - 14624) * 256 + t;
    ((ushort4*)(w1b + (size_t)4384 * 1024))[i] = ushort4{0, 0, 0, 0};
    return;
  }
  float4 v = ((const float4*)src)[i];
  ushort4 o;
  o.x = f2bf(v.x); o.y = f2bf(v.y); o.z = f2bf(v.z); o.w = f2bf(v.w);
  ((ushort4*)dst)[i] = o;
}

// ---------------- bf16 MFMA GEMM:  C[M][ldc] = A[M][K] * B[N][K]^T ----------------
// 128x128 tile, BK=32, double-buffered LDS with counted vmcnt (raw asm barriers:
// avoids __syncthreads' forced vmcnt(0) drain, the m97 structural stall).
template <int BF16OUT>
__global__ __launch_bounds__(256) void k_gemm(const u16* __restrict__ A,
                                              const u16* __restrict__ B, int K,
                                              int Nvalid, int ldc,
                                              u16* __restrict__ Cb,
                                              float* __restrict__ Cf,
                                              const float* __restrict__ resid,
                                              float* __restrict__ Cdt) {
  __shared__ __attribute__((aligned(16))) u16 As[2][128 * 32];
  __shared__ __attribute__((aligned(16))) u16 Bs[2][128 * 32];
  const int tid = threadIdx.x;
  const int lane = tid & 63;
  const int wid = tid >> 6;
  const int wm = wid >> 1, wn = wid & 1;
  const int m0 = blockIdx.x * 128, n0 = blockIdx.y * 128;

  f32x4 acc[4][4];
#pragma unroll
  for (int i = 0; i < 4; ++i)
#pragma unroll
    for (int j = 0; j < 4; ++j) acc[i][j] = f32x4{0.f, 0.f, 0.f, 0.f};

  // staging: wave wid stages 1KB chunks {2*wid, 2*wid+1} of As and Bs, linear.
  const char* gA[2]; const char* gB[2];
  int cbo[2];
#pragma unroll
  for (int j = 0; j < 2; ++j) {
    int base = (wid * 2 + j) * 1024;         // chunk byte base (wave-uniform)
    int p = base + lane * 16;
    int row = p >> 6;                        // 64B per LDS row (32 bf16)
    int colb = p & 63;
    gA[j] = (const char*)A + ((size_t)(m0 + row) * K) * 2 + colb;
    gB[j] = (const char*)B + ((size_t)(n0 + row) * K) * 2 + colb;
    cbo[j] = base;
  }

#define STAGE(bufi, kt) do { size_t kb = (size_t)(kt) * 64; \
    async16(gA[0] + kb, (char*)As[bufi] + cbo[0]); \
    async16(gA[1] + kb, (char*)As[bufi] + cbo[1]); \
    async16(gB[0] + kb, (char*)Bs[bufi] + cbo[0]); \
    async16(gB[1] + kb, (char*)Bs[bufi] + cbo[1]); } while (0)

  const int kg = (lane >> 4) * 16;
  const int rr = wm * 64 + (lane & 15);
  const int cc = wn * 64 + (lane & 15);

  STAGE(0, 0);
  const int nt = K >> 5;
  for (int t = 0; t < nt; ++t) {
    const int cur = t & 1;
    if (t + 1 < nt) {
      STAGE(cur ^ 1, t + 1);
      asm volatile("s_waitcnt vmcnt(4)" ::: "memory");  // oldest 4 (cur buf) landed
    } else {
      asm volatile("s_waitcnt vmcnt(0)" ::: "memory");
    }
    asm volatile("s_barrier" ::: "memory");             // all waves' chunks visible
    const u16* Ab = As[cur];
    const u16* Bb = Bs[cur];
    frag af[4], bfr[4];
#pragma unroll
    for (int mi = 0; mi < 4; ++mi)
      af[mi] = *(const frag*)((const char*)Ab + (rr + mi * 16) * 64 + kg);
#pragma unroll
    for (int ni = 0; ni < 4; ++ni)
      bfr[ni] = *(const frag*)((const char*)Bb + (cc + ni * 16) * 64 + kg);
#pragma unroll
    for (int mi = 0; mi < 4; ++mi)
#pragma unroll
      for (int ni = 0; ni < 4; ++ni)
        acc[mi][ni] = __builtin_amdgcn_mfma_f32_16x16x32_bf16(af[mi], bfr[ni],
                                                              acc[mi][ni], 0, 0, 0);
    asm volatile("s_waitcnt lgkmcnt(0)" ::: "memory");  // ds_reads of cur done
    asm volatile("s_barrier" ::: "memory");             // before next stage overwrites
  }
#undef STAGE

  const int er = (lane >> 4) * 4;
  const int ec = lane & 15;
#pragma unroll
  for (int mi = 0; mi < 4; ++mi) {
#pragma unroll
    for (int ni = 0; ni < 4; ++ni) {
      int col = n0 + wn * 64 + ni * 16 + ec;
      if (col < Nvalid) {
#pragma unroll
        for (int r = 0; r < 4; ++r) {
          int row = m0 + wm * 64 + mi * 16 + er + r;
          size_t off = (size_t)row * ldc + col;
          float v = acc[mi][ni][r];
          if (BF16OUT) {
            Cb[off] = f2bf(v);
            if (col >= D_INNER + CONV_DIM)
              Cdt[(size_t)row * NHEADS + (col - D_INNER - CONV_DIM)] = v;
          } else {
            Cf[off] = v + resid[off];
          }
        }
      }
    }
  }
}

// ---------------- depthwise causal conv(4) + bias + silu ----------------
// channels < 2048 -> xcb bf16 (stride 2048); channels >= 2048 (B,C) -> bcb bf16 (stride 256)
__global__ __launch_bounds__(256) void k_conv(const u16* __restrict__ zxb,
                                              const float* __restrict__ cw,
                                              const float* __restrict__ cb,
                                              u16* __restrict__ xcb,
                                              u16* __restrict__ bcb) {
  int row = blockIdx.x;          // b*L + l
  int l = row & (L_SEQ - 1);
  for (int c4 = threadIdx.x; c4 < CONV_DIM / 4; c4 += 256) {
    int c = c4 * 4;
    float4 w0 = ((const float4*)cw)[c + 0];
    float4 w1 = ((const float4*)cw)[c + 1];
    float4 w2 = ((const float4*)cw)[c + 2];
    float4 w3 = ((const float4*)cw)[c + 3];
    float4 bias = *(const float4*)(cb + c);
    float a0 = bias.x, a1 = bias.y, a2 = bias.z, a3 = bias.w;
#pragma unroll
    for (int k = 0; k < 4; ++k) {
      int lm = l - 3 + k;
      if (lm >= 0) {
        ushort4 xv = *(const ushort4*)(zxb + (size_t)(row - 3 + k) * D_IN_PROJ + D_INNER + c);
        a0 = fmaf(bf2f(xv.x), (&w0.x)[k], a0);
        a1 = fmaf(bf2f(xv.y), (&w1.x)[k], a1);
        a2 = fmaf(bf2f(xv.z), (&w2.x)[k], a2);
        a3 = fmaf(bf2f(xv.w), (&w3.x)[k], a3);
      }
    }
    a0 = a0 / (1.f + expf(-a0));
    a1 = a1 / (1.f + expf(-a1));
    a2 = a2 / (1.f + expf(-a2));
    a3 = a3 / (1.f + expf(-a3));
    ushort4 o;
    o.x = f2bf(a0); o.y = f2bf(a1); o.z = f2bf(a2); o.w = f2bf(a3);
    if (c < D_INNER) {
      *(ushort4*)(xcb + (size_t)row * D_INNER + c) = o;
    } else {
      *(ushort4*)(bcb + (size_t)row * 256 + (c - D_INNER)) = o;
    }
  }
}

// ---------------- dt, and in-chunk inclusive cumsum of dt*A ----------------
__global__ __launch_bounds__(128) void k_cum(const float* __restrict__ dtf,
                                             const float* __restrict__ dtb,
                                             const float* __restrict__ alog,
                                             float* __restrict__ dtv,
                                             float* __restrict__ cumv) {
  int bid = blockIdx.x;
  int c = bid & (NCH - 1);
  int bh = bid >> 4;
  int h = bh & 31, b = bh >> 5;
  int t = threadIdx.x;                 // 0..127
  int l = c * QC + t;
  float raw = dtf[((size_t)(b * L_SEQ + l)) * NHEADS + h] + dtb[h];
  float dt = raw > 20.f ? raw : log1pf(expf(raw));
  float A = -expf(alog[h]);
  float x = dt * A;
  int lane = t & 63;
#pragma unroll
  for (int off = 1; off < 64; off <<= 1) {
    float up = __shfl_up(x, off);
    if (lane >= off) x += up;
  }
  __shared__ float wtot;
  if (t == 63) wtot = x;
  __syncthreads();
  if (t >= 64) x += wtot;
  size_t o = (size_t)bh * L_SEQ + l;
  dtv[o] = dt;
  cumv[o] = x;
}

// ---------------- G = C @ B^T per (b, chunk)  [128x128, K=128] ----------------
__global__ __launch_bounds__(256) void k_g(const u16* __restrict__ bcb,
                                           u16* __restrict__ Gb) {
  __shared__ u16 Cs[128 * 128];   // A-op: C rows i, k=n
  __shared__ u16 Bs[128 * 128];   // B-op: B rows j, k=n
  int bid = blockIdx.x;
  int c = bid & (NCH - 1);
  int b = bid >> 4;
  int tid = threadIdx.x, lane = tid & 63, wid = tid >> 6;
  int wm = wid >> 1, wn = wid & 1;
  const u16* base = bcb + (size_t)(b * L_SEQ + c * QC) * 256;
  for (int idx = tid; idx < 128 * 32; idx += 256) {
    int row = idx >> 5, seg = idx & 31;
    u16x8 v = *(const u16x8*)(base + (size_t)row * 256 + seg * 8);
    if (seg < 16) *(u16x8*)&Bs[row * 128 + seg * 8] = v;
    else          *(u16x8*)&Cs[row * 128 + (seg - 16) * 8] = v;
  }
  __syncthreads();
  f32x4 acc[4][4];
#pragma unroll
  for (int i = 0; i < 4; ++i)
#pragma unroll
    for (int j = 0; j < 4; ++j) acc[i][j] = f32x4{0.f, 0.f, 0.f, 0.f};
  int rr = wm * 64 + (lane & 15);
  int cc = wn * 64 + (lane & 15);
#pragma unroll
  for (int kk = 0; kk < 4; ++kk) {
    int ko = kk * 32 + (lane >> 4) * 8;
    frag af[4], bfr[4];
#pragma unroll
    for (int mi = 0; mi < 4; ++mi)
      af[mi] = *(const frag*)&Cs[(rr + mi * 16) * 128 + ko];
#pragma unroll
    for (int ni = 0; ni < 4; ++ni)
      bfr[ni] = *(const frag*)&Bs[(cc + ni * 16) * 128 + ko];
#pragma unroll
    for (int mi = 0; mi < 4; ++mi)
#pragma unroll
      for (int ni = 0; ni < 4; ++ni)
        acc[mi][ni] = __builtin_amdgcn_mfma_f32_16x16x32_bf16(af[mi], bfr[ni],
                                                              acc[mi][ni], 0, 0, 0);
  }
  u16* gbase = Gb + ((size_t)(b * NCH + c)) * 128 * 128;
  const int er = (lane >> 4) * 4;
  const int ec = lane & 15;
#pragma unroll
  for (int mi = 0; mi < 4; ++mi)
#pragma unroll
    for (int ni = 0; ni < 4; ++ni)
#pragma unroll
      for (int r = 0; r < 4; ++r) {
        int i = wm * 64 + mi * 16 + er + r;
        int j = wn * 64 + ni * 16 + ec;
        gbase[(size_t)i * 128 + j] = f2bf(acc[mi][ni][r]);
      }
}

// ---------------- chunk states: S[p][n] = sum_j X[j][p] * B[j][n] * w[j] ----------------
__global__ __launch_bounds__(256) void k_states(const u16* __restrict__ xcb,
                                                const u16* __restrict__ bcb,
                                                const float* __restrict__ dtv,
                                                const float* __restrict__ cumv,
                                                u16* __restrict__ SH) {
  __shared__ u16 XT[64 * 136];     // A-op: X^T rows p, k=j
  __shared__ u16 BW[128 * 136];    // B-op: (wB)^T rows n, k=j
  __shared__ float wlds[128];
  int bid = blockIdx.x;
  int c = bid & (NCH - 1);
  int bh = bid >> 4;
  int h = bh & 31, b = bh >> 5;
  int tid = threadIdx.x, lane = tid & 63, wid = tid >> 6;
  int wm = wid >> 1, wn = wid & 1;
  int l0 = c * QC;
  size_t bhl = (size_t)bh * L_SEQ + l0;
  if (tid < 128) {
    float ce = cumv[bhl + 127];
    wlds[tid] = expf(ce - cumv[bhl + tid]) * dtv[bhl + tid];
  }
  // X^T scatter
  const u16* xbase = xcb + ((size_t)(b * L_SEQ + l0)) * D_INNER + h * HEADDIM;
  for (int idx = tid; idx < 128 * 8; idx += 256) {
    int j = idx >> 3, seg = idx & 7;
    u16x8 xv = *(const u16x8*)(xbase + (size_t)j * D_INNER + seg * 8);
#pragma unroll
    for (int k = 0; k < 8; ++k) XT[(seg * 8 + k) * 136 + j] = xv[k];
  }
  __syncthreads();
  // (wB)^T scatter (B now bf16)
  const u16* bbase = bcb + (size_t)(b * L_SEQ + l0) * 256;
  for (int idx = tid; idx < 128 * 16; idx += 256) {
    int j = idx >> 4, seg = idx & 15;
    u16x8 bv = *(const u16x8*)(bbase + (size_t)j * 256 + seg * 8);
    float w = wlds[j];
#pragma unroll
    for (int k = 0; k < 8; ++k)
      BW[(seg * 8 + k) * 136 + j] = f2bf(bf2f(bv[k]) * w);
  }
  __syncthreads();
  f32x4 acc[2][4];
#pragma unroll
  for (int i = 0; i < 2; ++i)
#pragma unroll
    for (int j = 0; j < 4; ++j) acc[i][j] = f32x4{0.f, 0.f, 0.f, 0.f};
  int rr = wm * 32 + (lane & 15);
  int cc = wn * 64 + (lane & 15);
#pragma unroll
  for (int kk = 0; kk < 4; ++kk) {
    int ko = kk * 32 + (lane >> 4) * 8;
    frag af[2], bfr[4];
#pragma unroll
    for (int mi = 0; mi < 2; ++mi)
      af[mi] = *(const frag*)&XT[(rr + mi * 16) * 136 + ko];
#pragma unroll
    for (int ni = 0; ni < 4; ++ni)
      bfr[ni] = *(const frag*)&BW[(cc + ni * 16) * 136 + ko];
#pragma unroll
    for (int mi = 0; mi < 2; ++mi)
#pragma unroll
      for (int ni = 0; ni < 4; ++ni)
        acc[mi][ni] = __builtin_amdgcn_mfma_f32_16x16x32_bf16(af[mi], bfr[ni],
                                                              acc[mi][ni], 0, 0, 0);
  }
  u16* sbase = SH + ((size_t)(bh * NCH + c)) * (64 * 128);
  const int er = (lane >> 4) * 4;
  const int ec = lane & 15;
#pragma unroll
  for (int mi = 0; mi < 2; ++mi)
#pragma unroll
    for (int ni = 0; ni < 4; ++ni)
#pragma unroll
      for (int r = 0; r < 4; ++r) {
        int p = wm * 32 + mi * 16 + er + r;
        int n = wn * 64 + ni * 16 + ec;
        sbase[(size_t)p * 128 + n] = f2bf(acc[mi][ni][r]);
      }
}

// ---------------- inter-chunk chain (in place: slot c becomes H_in for chunk c) ----------------
__global__ __launch_bounds__(512) void k_chain(u16* __restrict__ SH,
                                               const float* __restrict__ cumv) {
  int bh = blockIdx.x;
  int t = threadIdx.x;
  u16* base = SH + (size_t)bh * NCH * (64 * 128) + t * 16;
  float H[16];
#pragma unroll
  for (int i = 0; i < 16; ++i) H[i] = 0.f;
  for (int c = 0; c < NCH; ++c) {
    u16x8 s0 = *(const u16x8*)(base + (size_t)c * 8192);
    u16x8 s1 = *(const u16x8*)(base + (size_t)c * 8192 + 8);
    float e = expf(cumv[(size_t)bh * L_SEQ + c * QC + 127]);
    u16x8 h0, h1;
#pragma unroll
    for (int k = 0; k < 8; ++k) { h0[k] = f2bf(H[k]); h1[k] = f2bf(H[k + 8]); }
    *(u16x8*)(base + (size_t)c * 8192) = h0;
    *(u16x8*)(base + (size_t)c * 8192 + 8) = h1;
#pragma unroll
    for (int k = 0; k < 8; ++k) {
      H[k] = fmaf(H[k], e, bf2f(s0[k]));
      H[k + 8] = fmaf(H[k + 8], e, bf2f(s1[k]));
    }
  }
}

// ---------------- Y = M@X^T + exp(cum_i)*(C@H^T) per (b,h,c)  [128x64] ----------------
__global__ __launch_bounds__(256) void k_y(const u16* __restrict__ xcb,
                                           const u16* __restrict__ bcb,
                                           const float* __restrict__ dtv,
                                           const float* __restrict__ cumv,
                                           const u16* __restrict__ Gb,
                                           const u16* __restrict__ SH,
                                           u16* __restrict__ ysb) {
  __shared__ u16 Abuf[128 * 136];
  __shared__ u16 Bbuf[64 * 136];
  __shared__ float cums[128], dts[128];
  int bid = blockIdx.x;
  int c = bid & (NCH - 1);
  int bh = bid >> 4;
  int h = bh & 31, b = bh >> 5;
  int tid = threadIdx.x, lane = tid & 63, wid = tid >> 6;
  int wm = wid >> 1, wn = wid & 1;
  int l0 = c * QC;
  size_t bhl = (size_t)bh * L_SEQ + l0;
  if (tid < 128) { cums[tid] = cumv[bhl + tid]; dts[tid] = dtv[bhl + tid]; }
  // X^T scatter into Bbuf
  const u16* xbase = xcb + ((size_t)(b * L_SEQ + l0)) * D_INNER + h * HEADDIM;
  for (int idx = tid; idx < 128 * 8; idx += 256) {
    int j = idx >> 3, seg = idx & 7;
    u16x8 xv = *(const u16x8*)(xbase + (size_t)j * D_INNER + seg * 8);
#pragma unroll
    for (int k = 0; k < 8; ++k) Bbuf[(seg * 8 + k) * 136 + j] = xv[k];
  }
  __syncthreads();
  // M = mask(G) * exp(cum_i - cum_j) * dt_j  into Abuf
  const u16* gbase = Gb + ((size_t)(b * NCH + c)) * 128 * 128;
  for (int idx = tid; idx < 128 * 16; idx += 256) {
    int i = idx >> 4, seg = idx & 15;
    u16x8 g = *(const u16x8*)(gbase + (size_t)i * 128 + seg * 8);
    float ci = cums[i];
    u16x8 o;
#pragma unroll
    for (int k = 0; k < 8; ++k) {
      int j = seg * 8 + k;
      float m = (j <= i) ? bf2f(g[k]) * expf(ci - cums[j]) * dts[j] : 0.f;
      o[k] = f2bf(m);
    }
    *(u16x8*)&Abuf[i * 136 + seg * 8] = o;
  }
  __syncthreads();
  f32x4 acc1[4][2], acc2[4][2];
#pragma unroll
  for (int i = 0; i < 4; ++i)
#pragma unroll
    for (int j = 0; j < 2; ++j) {
      acc1[i][j] = f32x4{0.f, 0.f, 0.f, 0.f};
      acc2[i][j] = f32x4{0.f, 0.f, 0.f, 0.f};
    }
  int rr = wm * 64 + (lane & 15);
  int cc = wn * 32 + (lane & 15);
#pragma unroll
  for (int kk = 0; kk < 4; ++kk) {
    int ko = kk * 32 + (lane >> 4) * 8;
    frag af[4], bfr[2];
#pragma unroll
    for (int mi = 0; mi < 4; ++mi)
      af[mi] = *(const frag*)&Abuf[(rr + mi * 16) * 136 + ko];
#pragma unroll
    for (int ni = 0; ni < 2; ++ni)
      bfr[ni] = *(const frag*)&Bbuf[(cc + ni * 16) * 136 + ko];
#pragma unroll
    for (int mi = 0; mi < 4; ++mi)
#pragma unroll
      for (int ni = 0; ni < 2; ++ni)
        acc1[mi][ni] = __builtin_amdgcn_mfma_f32_16x16x32_bf16(af[mi], bfr[ni],
                                                               acc1[mi][ni], 0, 0, 0);
  }
  __syncthreads();
  // pass 2: raw C rows (bf16) into Abuf; H[p][n] into Bbuf; exp(cum_i) factored out
  const u16* cbase = bcb + (size_t)(b * L_SEQ + l0) * 256 + 128;
  for (int idx = tid; idx < 128 * 16; idx += 256) {
    int i = idx >> 4, seg = idx & 15;
    *(u16x8*)&Abuf[i * 136 + seg * 8] = *(const u16x8*)(cbase + (size_t)i * 256 + seg * 8);
  }
  const u16* hbase = SH + ((size_t)(bh * NCH + c)) * (64 * 128);
  for (int idx = tid; idx < 64 * 16; idx += 256) {
    int p = idx >> 4, seg = idx & 15;
    *(u16x8*)&Bbuf[p * 136 + seg * 8] = *(const u16x8*)(hbase + (size_t)p * 128 + seg * 8);
  }
  __syncthreads();
#pragma unroll
  for (int kk = 0; kk < 4; ++kk) {
    int ko = kk * 32 + (lane >> 4) * 8;
    frag af[4], bfr[2];
#pragma unroll
    for (int mi = 0; mi < 4; ++mi)
      af[mi] = *(const frag*)&Abuf[(rr + mi * 16) * 136 + ko];
#pragma unroll
    for (int ni = 0; ni < 2; ++ni)
      bfr[ni] = *(const frag*)&Bbuf[(cc + ni * 16) * 136 + ko];
#pragma unroll
    for (int mi = 0; mi < 4; ++mi)
#pragma unroll
      for (int ni = 0; ni < 2; ++ni)
        acc2[mi][ni] = __builtin_amdgcn_mfma_f32_16x16x32_bf16(af[mi], bfr[ni],
                                                               acc2[mi][ni], 0, 0, 0);
  }
  const int er = (lane >> 4) * 4;
  const int ec = lane & 15;
#pragma unroll
  for (int mi = 0; mi < 4; ++mi)
#pragma unroll
    for (int r = 0; r < 4; ++r) {
      int i = wm * 64 + mi * 16 + er + r;
      float e = expf(cums[i]);
#pragma unroll
      for (int ni = 0; ni < 2; ++ni) {
        int p = wn * 32 + ni * 16 + ec;
        float v = acc1[mi][ni][r] + e * acc2[mi][ni][r];
        ysb[((size_t)(b * L_SEQ + l0 + i)) * D_INNER + h * HEADDIM + p] = f2bf(v);
      }
    }
}

// ---------------- y = (ys + D*x_ssm)*silu(z), RMSNorm, -> bf16 ----------------
__global__ __launch_bounds__(256) void k_gate(const u16* __restrict__ ysb,
                                              const u16* __restrict__ xcb,
                                              const u16* __restrict__ zxb,
                                              const float* __restrict__ Dp,
                                              const float* __restrict__ nw,
                                              u16* __restrict__ yb) {
  int row = blockIdx.x;
  int t = threadIdx.x;
  int d0 = t * 8;
  float Dh = Dp[d0 >> 6];
  u16x8 ya = *(const u16x8*)(ysb + (size_t)row * D_INNER + d0);
  u16x8 xa = *(const u16x8*)(xcb + (size_t)row * D_INNER + d0);
  u16x8 za = *(const u16x8*)(zxb + (size_t)row * D_IN_PROJ + d0);
  float v[8];
  float ss = 0.f;
#pragma unroll
  for (int c = 0; c < 8; ++c) {
    float val = bf2f(ya[c]) + Dh * bf2f(xa[c]);
    float zz = bf2f(za[c]);
    val *= zz / (1.f + expf(-zz));
    v[c] = val;
    ss += val * val;
  }
  __shared__ float red[4];
#pragma unroll
  for (int off = 32; off; off >>= 1) ss += __shfl_xor(ss, off);
  if ((t & 63) == 0) red[t >> 6] = ss;
  __syncthreads();
  float tot = red[0] + red[1] + red[2] + red[3];
  float scale = rsqrtf(tot * (1.f / D_INNER) + EPSF);
  float4 w0 = *(const float4*)(nw + d0);
  float4 w1 = *(const float4*)(nw + d0 + 4);
  u16x8 o;
  o[0] = f2bf(v[0] * scale * w0.x);
  o[1] = f2bf(v[1] * scale * w0.y);
  o[2] = f2bf(v[2] * scale * w0.z);
  o[3] = f2bf(v[3] * scale * w0.w);
  o[4] = f2bf(v[4] * scale * w1.x);
  o[5] = f2bf(v[5] * scale * w1.y);
  o[6] = f2bf(v[6] * scale * w1.z);
  o[7] = f2bf(v[7] * scale * w1.w);
  *(u16x8*)(yb + (size_t)row * D_INNER + d0) = o;
}

// ---------------- final LayerNorm (in-place on d_out) ----------------
union F4 { float4 v; float f[4]; };
__global__ __launch_bounds__(256) void k_ln(float* __restrict__ io,
                                            const float* __restrict__ lw,
                                            const float* __restrict__ lb) {
  int row = blockIdx.x;
  int t = threadIdx.x;
  int d0 = t * 4;
  F4 v; v.v = *(const float4*)(io + (size_t)row * D_MODEL + d0);
  float s1 = v.f[0] + v.f[1] + v.f[2] + v.f[3];
  float s2 = v.f[0] * v.f[0] + v.f[1] * v.f[1] + v.f[2] * v.f[2] + v.f[3] * v.f[3];
  __shared__ float r1[4], r2[4];
#pragma unroll
  for (int off = 32; off; off >>= 1) {
    s1 += __shfl_xor(s1, off);
    s2 += __shfl_xor(s2, off);
  }
  if ((t & 63) == 0) { r1[t >> 6] = s1; r2[t >> 6] = s2; }
  __syncthreads();
  float S1 = r1[0] + r1[1] + r1[2] + r1[3];
  float S2 = r2[0] + r2[1] + r2[2] + r2[3];
  float mu = S1 * (1.f / D_MODEL);
  float var = S2 * (1.f / D_MODEL) - mu * mu;
  float inv = rsqrtf(var + EPSF);
  F4 w, bb, o;
  w.v = *(const float4*)(lw + d0);
  bb.v = *(const float4*)(lb + d0);
#pragma unroll
  for (int c = 0; c < 4; ++c) o.f[c] = (v.f[c] - mu) * inv * w.f[c] + bb.f[c];
  *(float4*)(io + (size_t)row * D_MODEL + d0) = o.v;
}

extern "C" void kernel_launch(void* const* d_in, const int* in_sizes, int n_in,
                              void* d_out, int out_size, void* d_ws, size_t ws_size,
                              hipStream_t stream) {
  const float* x    = (const float*)d_in[0];
  const float* w1   = (const float*)d_in[1];
  const float* cw   = (const float*)d_in[2];
  const float* cb   = (const float*)d_in[3];
  const float* dtb  = (const float*)d_in[4];
  const float* alog = (const float*)d_in[5];
  const float* Dp   = (const float*)d_in[6];
  const float* nw   = (const float*)d_in[7];
  const float* w2   = (const float*)d_in[8];
  const float* lw   = (const float*)d_in[9];
  const float* lb   = (const float*)d_in[10];
  float* out = (float*)d_out;
  char* ws = (char*)d_ws;

  // workspace layout (bytes)
  u16*   xb   = (u16*)(ws + 0);            // 8192x1024 bf16  16,777,216
  u16*   w1b  = (u16*)(ws + 16777216);     // 4480x1024 bf16   9,175,040
  u16*   w2b  = (u16*)(ws + 25952256);     // 1024x2048 bf16   4,194,304
  u16*   zxb  = (u16*)(ws + 30146560);     // 8192x4384 bf16  71,827,456
  u16*   xcb  = (u16*)(ws + 101974016);    // 8192x2048 bf16  33,554,432
  float* dtf  = (float*)(ws + 135528448);  // 8192x32 f32      1,048,576
  float* dtv  = (float*)(ws + 136577024);  // 128x2048 f32     1,048,576
  float* cumv = (float*)(ws + 137625600);  // 128x2048 f32     1,048,576
  u16*   ysb  = (u16*)(ws + 138674176);    // 8192x2048 bf16  33,554,432
  u16*   yb   = (u16*)(ws + 172228608);    // 8192x2048 bf16  33,554,432
  u16*   Gb   = (u16*)(ws + 205783040);    // 64x128x128 bf16  4,194,304
  // total: 209,977,344 (proven available)
  if (ws_size < (size_t)209977344) return;

  u16* bcb = (u16*)out;      // d_out as B/C bf16 scratch (8192x256) until out_proj
  u16* SH  = yb;             // chunk states bf16 [bh][c][64][128] in yb until k_gate

  k_cvt_all<<<14720, 256, 0, stream>>>(x, xb, w1, w1b, w2, w2b);

  // in_proj: zx[8192][4384] = xb @ w1b^T (bf16 out + f32 dt copy)
  k_gemm<1><<<dim3(64, 35), 256, 0, stream>>>(xb, w1b, 1024, 4384, 4384,
                                              zxb, nullptr, nullptr, dtf);

  k_conv<<<8192, 256, 0, stream>>>(zxb, cw, cb, xcb, bcb);
  k_cum<<<128 * NCH, 128, 0, stream>>>(dtf, dtb, alog, dtv, cumv);

  k_g<<<4 * NCH, 256, 0, stream>>>(bcb, Gb);
  k_states<<<128 * NCH, 256, 0, stream>>>(xcb, bcb, dtv, cumv, SH);
  k_chain<<<128, 512, 0, stream>>>(SH, cumv);
  k_y<<<128 * NCH, 256, 0, stream>>>(xcb, bcb, dtv, cumv, Gb, SH, ysb);

  k_gate<<<8192, 256, 0, stream>>>(ysb, xcb, zxb, Dp, nw, yb);

  // out_proj + residual: out = yb @ w2b^T + x
  k_gemm<0><<<dim3(64, 8), 256, 0, stream>>>(yb, w2b, 2048, 1024, 1024,
                                             nullptr, out, x, nullptr);

  k_ln<<<8192, 256, 0, stream>>>(out, lw, lb);
}